// Round 8
// baseline (386.817 us; speedup 1.0000x reference)
//
#include <hip/hip_runtime.h>

#define NN 100000
#define NE 600000
#define NG 64
#define FD 128
#define NB 98   // scan blocks of 1024: 98*1024 >= NN
#define EPAD 900000  // padded edge capacity: NE + 3*NN

typedef __attribute__((ext_vector_type(8))) short s8v;
typedef __attribute__((ext_vector_type(4))) float f4v;

__device__ inline float bflo(unsigned u) { return __uint_as_float(u << 16); }
__device__ inline float bfhi(unsigned u) { return __uint_as_float(u & 0xFFFF0000u); }
__device__ inline unsigned f2bfbits(float f) {  // round-to-nearest-even
  unsigned x = __float_as_uint(f);
  return (x + 0x7FFFu + ((x >> 16) & 1u)) >> 16;
}
__device__ inline unsigned pack2(float a, float b) { return f2bfbits(a) | (f2bfbits(b) << 16); }

// ---------------- weight cast: W f32 [K][N] -> WThi/WTlo bf16 [N][K], 3 weights in one ----------------
__global__ void k_castW3(const float* __restrict__ W1, const float* __restrict__ W2,
                         const float* __restrict__ W3, unsigned short* __restrict__ WTh,
                         unsigned short* __restrict__ WTl) {
  int e = blockIdx.x * 256 + threadIdx.x;   // grid covers 3*FD*FD
  int which = e / (FD * FD);
  int r = e - which * (FD * FD);
  if (which >= 3) return;
  const float* W = which == 0 ? W1 : (which == 1 ? W2 : W3);
  int k = r >> 7, n = r & 127;
  float v = W[r];
  unsigned hb = f2bfbits(v);
  float hf = __uint_as_float(hb << 16);
  unsigned lb = f2bfbits(v - hf);
  WTh[which * FD * FD + n * FD + k] = (unsigned short)hb;
  WTl[which * FD * FD + n * FD + k] = (unsigned short)lb;
}

// ---------------- degree / CSR build ----------------

__global__ void k_init(float* psum) {
  int i = blockIdx.x * 256 + threadIdx.x;
  if (i < NG * FD) psum[i] = 0.f;
}

__global__ void k_count(const int* __restrict__ col, int* __restrict__ counts) {
  int e = blockIdx.x * 256 + threadIdx.x;
  if (e < NE) atomicAdd(&counts[col[e]], 1);
}

__global__ void k_dinv(const int* __restrict__ counts, float* __restrict__ dinv) {
  int n = blockIdx.x * 256 + threadIdx.x;
  if (n < NN) dinv[n] = rsqrtf((float)counts[n] + 1.0f);
}

// 3-phase scan over PADDED counts: ceil(deg/4)*4 per node
__global__ void k_bsum(const int* __restrict__ counts, int* __restrict__ bsum) {
  __shared__ int wsm[16];
  int b = blockIdx.x, t = threadIdx.x;
  int i = b * 1024 + t;
  int x = (i < NN) ? ((counts[i] + 3) & ~3) : 0;
#pragma unroll
  for (int d = 32; d; d >>= 1) x += __shfl_down(x, d);
  if ((t & 63) == 0) wsm[t >> 6] = x;
  __syncthreads();
  if (t < 16) {
    int s = wsm[t];
#pragma unroll
    for (int d = 8; d; d >>= 1) s += __shfl_down(s, d);
    if (t == 0) bsum[b] = s;
  }
}

__global__ void k_bscan(const int* __restrict__ bsum, int* __restrict__ eb) {
  __shared__ int w0;
  int t = threadIdx.x;  // 128
  int x = (t < NB) ? bsum[t] : 0;
  int lane = t & 63;
  int inc = x;
#pragma unroll
  for (int d = 1; d < 64; d <<= 1) { int y = __shfl_up(inc, d); if (lane >= d) inc += y; }
  if (t == 63) w0 = inc;
  __syncthreads();
  int off = (t >= 64) ? w0 : 0;
  if (t < NB) eb[t] = off + inc - x;  // exclusive
}

__global__ void k_scan2(const int* __restrict__ counts, const int* __restrict__ eb,
                        int* __restrict__ indptr) {
  __shared__ int wsm[16];
  int b = blockIdx.x, t = threadIdx.x;
  int i = b * 1024 + t;
  int x = (i < NN) ? ((counts[i] + 3) & ~3) : 0;
  int lane = t & 63, wid = t >> 6;
  int inc = x;
#pragma unroll
  for (int d = 1; d < 64; d <<= 1) { int y = __shfl_up(inc, d); if (lane >= d) inc += y; }
  if (lane == 63) wsm[wid] = inc;
  __syncthreads();
  if (wid == 0) {
    int s = (lane < 16) ? wsm[lane] : 0;
#pragma unroll
    for (int d = 1; d < 16; d <<= 1) { int y = __shfl_up(s, d); if (lane >= d) s += y; }
    if (lane < 16) wsm[lane] = s;
  }
  __syncthreads();
  int woff = wid ? wsm[wid - 1] : 0;
  if (i < NN) indptr[i + 1] = eb[b] + woff + inc;
  if (i == 0) indptr[0] = 0;
}

// combined edge record: {src, nrm}; pad slots stay {0, 0.0f} from memset (exact no-ops)
__global__ void k_fill(const int* __restrict__ row, const int* __restrict__ col,
                       const int* __restrict__ indptr, int* __restrict__ cursor,
                       const float* __restrict__ dinv, uint2* __restrict__ edges) {
  int e = blockIdx.x * 256 + threadIdx.x;
  if (e >= NE) return;
  int c = col[e], r = row[e];
  int p = indptr[c] + atomicAdd(&cursor[c], 1);
  edges[p] = make_uint2((unsigned)r, __float_as_uint(dinv[r] * dinv[c]));
}

// batch is sorted: ranges by boundary detection
__global__ void k_ranges(const int* __restrict__ batch, int* __restrict__ starts,
                         int* __restrict__ ends) {
  int n = blockIdx.x * 256 + threadIdx.x;
  if (n >= NN) return;
  int g = batch[n];
  if (n == 0) {
    starts[g] = 0;
    for (int q = 0; q < g; ++q) { starts[q] = 0; ends[q] = 0; }
  } else {
    int gp = batch[n - 1];
    if (gp != g) {
      ends[gp] = n;
      starts[g] = n;
      for (int q = gp + 1; q < g; ++q) { starts[q] = n; ends[q] = n; }
    }
  }
  if (n == NN - 1) {
    ends[g] = NN;
    for (int q = g + 1; q < NG; ++q) { starts[q] = NN; ends[q] = NN; }
  }
}

// ---------------- MFMA GEMM: Hb[M,128] = A[M,128] @ (WThi+WTlo)^T ----------------
// Barrier-free, LDS-free; one wave owns 16 rows. B-fragments are loaded in
// register batches of 8 (explicit MLP), then consumed by 8 MFMAs — latency is
// paid ~8x per wave instead of 64x (R7's serial-chain failure mode).
template <int F32A>
__global__ __launch_bounds__(256) void k_gemm(const void* __restrict__ Aab,
                                              const unsigned short* __restrict__ WThi,
                                              const unsigned short* __restrict__ WTlo,
                                              unsigned short* __restrict__ Hb, int M) {
  int wv = (blockIdx.x * 256 + threadIdx.x) >> 6;  // global wave id
  int lane = threadIdx.x & 63;
  int r16 = lane & 15, kg = lane >> 4;
  int rowBase = wv * 16;
  if (rowBase >= M) return;

  f4v acc[8];
#pragma unroll
  for (int n = 0; n < 8; ++n) acc[n] = (f4v){0.f, 0.f, 0.f, 0.f};

  // A fragments: lane holds A[row=r16][k = c*32 + kg*8 + j]
  s8v afr[4];
  {
    int ar = rowBase + r16;
    if (ar > M - 1) ar = M - 1;
    if (F32A) {
      const float* ap = (const float*)Aab + (size_t)ar * FD + kg * 8;
#pragma unroll
      for (int c = 0; c < 4; ++c) {
        float4 p0 = *(const float4*)(ap + c * 32);
        float4 p1 = *(const float4*)(ap + c * 32 + 4);
        s8v f;
        f[0] = (short)f2bfbits(p0.x); f[1] = (short)f2bfbits(p0.y);
        f[2] = (short)f2bfbits(p0.z); f[3] = (short)f2bfbits(p0.w);
        f[4] = (short)f2bfbits(p1.x); f[5] = (short)f2bfbits(p1.y);
        f[6] = (short)f2bfbits(p1.z); f[7] = (short)f2bfbits(p1.w);
        afr[c] = f;
      }
    } else {
      const unsigned short* ap = (const unsigned short*)Aab + (size_t)ar * FD + kg * 8;
#pragma unroll
      for (int c = 0; c < 4; ++c) afr[c] = *(const s8v*)(ap + c * 32);
    }
  }

#pragma unroll 1   // keep hi/lo passes separate to cap VGPR pressure
  for (int pass = 0; pass < 2; ++pass) {
    const unsigned short* wp = (pass ? WTlo : WThi) + r16 * FD + kg * 8;
#pragma unroll
    for (int h = 0; h < 4; ++h) {          // n = h*2 + q, q in {0,1}
      s8v bfr[8];
#pragma unroll
      for (int q = 0; q < 2; ++q)
#pragma unroll
        for (int c = 0; c < 4; ++c)
          bfr[q * 4 + c] = *(const s8v*)(wp + (size_t)((h * 2 + q) * 16) * FD + c * 32);
#pragma unroll
      for (int q = 0; q < 2; ++q)
#pragma unroll
        for (int c = 0; c < 4; ++c)
          acc[h * 2 + q] =
              __builtin_amdgcn_mfma_f32_16x16x32_bf16(afr[c], bfr[q * 4 + c], acc[h * 2 + q], 0, 0, 0);
    }
  }

  // epilogue: D lane layout col = r16, row = kg*4 + j
#pragma unroll
  for (int j = 0; j < 4; ++j) {
    int r = rowBase + kg * 4 + j;
    if (r < M) {
#pragma unroll
      for (int n = 0; n < 8; ++n)
        Hb[(size_t)r * FD + n * 16 + r16] = (unsigned short)f2bfbits(acc[n][j]);
    }
  }
}

// ---------------- aggregation: 2 nodes per wave (32-lane halves), uint2 lanes ----------------
// CSR segments are padded to multiples of 4 -> single branch-free 4-unrolled loop.
__global__ __launch_bounds__(256) void k_agg(const uint2* __restrict__ H2,
                                             const int* __restrict__ indptr,
                                             const uint2* __restrict__ edges,
                                             const float* __restrict__ dinv,
                                             const float* __restrict__ bias,
                                             uint2* __restrict__ out2, int relu) {
  int wid = (blockIdx.x * 256 + threadIdx.x) >> 6;  // global wave id
  int hl = threadIdx.x & 31;                        // lane within half
  int n = wid * 2 + ((threadIdx.x >> 5) & 1);       // node of this half
  if (n >= NN) return;
  float dv = dinv[n];
  float s2 = dv * dv;
  uint2 u = H2[(size_t)n * 32 + hl];
  float a0 = s2 * bflo(u.x), a1 = s2 * bfhi(u.x);
  float a2 = s2 * bflo(u.y), a3 = s2 * bfhi(u.y);
  int e0 = indptr[n], e1 = indptr[n + 1];  // e1-e0 is a multiple of 4
  for (int e = e0; e < e1; e += 4) {
    uint2 q0 = edges[e], q1 = edges[e + 1], q2 = edges[e + 2], q3 = edges[e + 3];
    uint2 v0 = H2[(size_t)q0.x * 32 + hl];
    uint2 v1 = H2[(size_t)q1.x * 32 + hl];
    uint2 v2 = H2[(size_t)q2.x * 32 + hl];
    uint2 v3 = H2[(size_t)q3.x * 32 + hl];
    float w0 = __uint_as_float(q0.y), w1 = __uint_as_float(q1.y);
    float w2 = __uint_as_float(q2.y), w3 = __uint_as_float(q3.y);
    a0 += w0 * bflo(v0.x); a1 += w0 * bfhi(v0.x); a2 += w0 * bflo(v0.y); a3 += w0 * bfhi(v0.y);
    a0 += w1 * bflo(v1.x); a1 += w1 * bfhi(v1.x); a2 += w1 * bflo(v1.y); a3 += w1 * bfhi(v1.y);
    a0 += w2 * bflo(v2.x); a1 += w2 * bfhi(v2.x); a2 += w2 * bflo(v2.y); a3 += w2 * bfhi(v2.y);
    a0 += w3 * bflo(v3.x); a1 += w3 * bfhi(v3.x); a2 += w3 * bflo(v3.y); a3 += w3 * bfhi(v3.y);
  }
  a0 += bias[hl * 4];
  a1 += bias[hl * 4 + 1];
  a2 += bias[hl * 4 + 2];
  a3 += bias[hl * 4 + 3];
  if (relu) {
    a0 = fmaxf(a0, 0.f); a1 = fmaxf(a1, 0.f);
    a2 = fmaxf(a2, 0.f); a3 = fmaxf(a3, 0.f);
  }
  out2[(size_t)n * 32 + hl] = make_uint2(pack2(a0, a1), pack2(a2, a3));
}

// ---------------- mean pool: wave per 64-node chunk, lanes cover row as bf16x2 ----------------
#define PW 64  // nodes per wave
__global__ __launch_bounds__(256) void k_pool(const unsigned* __restrict__ H2,
                                              const int* __restrict__ batch,
                                              float* __restrict__ psum) {
  int wgl = (blockIdx.x * 256 + threadIdx.x) >> 6;  // global wave id
  int lane = threadIdx.x & 63;
  int n0 = wgl * PW;
  if (n0 >= NN) return;
  int n1 = n0 + PW; if (n1 > NN) n1 = NN;
  int g0 = batch[n0], g1 = batch[n1 - 1];
  float a0 = 0.f, a1 = 0.f;
  if (g0 == g1) {
    int n = n0;
    for (; n + 3 < n1; n += 4) {
      unsigned v0 = H2[(size_t)(n + 0) * 64 + lane];
      unsigned v1 = H2[(size_t)(n + 1) * 64 + lane];
      unsigned v2 = H2[(size_t)(n + 2) * 64 + lane];
      unsigned v3 = H2[(size_t)(n + 3) * 64 + lane];
      a0 += bflo(v0) + bflo(v1) + bflo(v2) + bflo(v3);
      a1 += bfhi(v0) + bfhi(v1) + bfhi(v2) + bfhi(v3);
    }
    for (; n < n1; ++n) {
      unsigned v = H2[(size_t)n * 64 + lane];
      a0 += bflo(v); a1 += bfhi(v);
    }
    atomicAdd(&psum[g0 * FD + lane * 2], a0);
    atomicAdd(&psum[g0 * FD + lane * 2 + 1], a1);
  } else {
    int g = g0;
    for (int n = n0; n < n1; ++n) {
      int gn = batch[n];
      if (gn != g) {
        atomicAdd(&psum[g * FD + lane * 2], a0);
        atomicAdd(&psum[g * FD + lane * 2 + 1], a1);
        a0 = 0.f; a1 = 0.f; g = gn;
      }
      unsigned v = H2[(size_t)n * 64 + lane];
      a0 += bflo(v); a1 += bfhi(v);
    }
    atomicAdd(&psum[g * FD + lane * 2], a0);
    atomicAdd(&psum[g * FD + lane * 2 + 1], a1);
  }
}

__global__ void k_head(const float* __restrict__ psum, const int* __restrict__ starts,
                       const int* __restrict__ ends, const float* __restrict__ Wl,
                       const float* __restrict__ bl, float* __restrict__ out) {
  int t = threadIdx.x;  // 128 = 64 graphs x 2 classes
  int g = t >> 1, c = t & 1;
  int cnt = ends[g] - starts[g];
  if (cnt < 0) cnt = 0;
  float inv = 1.f / (float)(cnt > 0 ? cnt : 1);
  float acc = 0.f;
  for (int k = 0; k < FD; ++k) acc += psum[g * FD + k] * Wl[k * 2 + c];
  out[g * 2 + c] = acc * inv + bl[c];
}

// ---------------- host ----------------

extern "C" void kernel_launch(void* const* d_in, const int* in_sizes, int n_in,
                              void* d_out, int out_size, void* d_ws, size_t ws_size,
                              hipStream_t stream) {
  const float* x  = (const float*)d_in[0];
  const int* ei   = (const int*)d_in[1];
  const int* bat  = (const int*)d_in[2];
  const float* W1 = (const float*)d_in[3];
  const float* b1 = (const float*)d_in[4];
  const float* W2 = (const float*)d_in[5];
  const float* b2 = (const float*)d_in[6];
  const float* W3 = (const float*)d_in[7];
  const float* b3 = (const float*)d_in[8];
  const float* Wl = (const float*)d_in[9];
  const float* bl = (const float*)d_in[10];
  float* out = (float*)d_out;

  char* ws = (char*)d_ws;
  size_t off = 0;
  auto alloc = [&](size_t bytes) {
    void* p = ws + off;
    off += (bytes + 255) & ~(size_t)255;
    return p;
  };
  int* counts  = (int*)alloc(NN * 4);
  int* cursor  = (int*)alloc(NN * 4);
  int* indptr  = (int*)alloc((NN + 1) * 4);
  float* dinv  = (float*)alloc(NN * 4);
  int* bsum    = (int*)alloc(NB * 4);
  int* eb      = (int*)alloc(NB * 4);
  int* starts  = (int*)alloc(NG * 4);
  int* ends    = (int*)alloc(NG * 4);
  float* psum  = (float*)alloc(NG * FD * 4);
  uint2* edges = (uint2*)alloc((size_t)EPAD * 8);
  unsigned short* Hb   = (unsigned short*)alloc((size_t)NN * FD * 2);
  unsigned short* Abuf = (unsigned short*)alloc((size_t)NN * FD * 2);
  unsigned short* WTh  = (unsigned short*)alloc(3 * FD * FD * 2);
  unsigned short* WTl  = (unsigned short*)alloc(3 * FD * FD * 2);

  const int* row = ei;
  const int* col = ei + NE;

  // counts + cursor are adjacent in ws: single memset covers both (and the pad gap)
  hipMemsetAsync(counts, 0, (size_t)((char*)cursor - (char*)counts) + NN * 4, stream);
  hipMemsetAsync(edges, 0, (size_t)EPAD * 8, stream);
  k_init<<<32, 256, 0, stream>>>(psum);
  k_castW3<<<(3 * FD * FD + 255) / 256, 256, 0, stream>>>(W1, W2, W3, WTh, WTl);
  k_ranges<<<(NN + 255) / 256, 256, 0, stream>>>(bat, starts, ends);
  k_count<<<(NE + 255) / 256, 256, 0, stream>>>(col, counts);
  k_dinv<<<(NN + 255) / 256, 256, 0, stream>>>(counts, dinv);
  k_bsum<<<NB, 1024, 0, stream>>>(counts, bsum);
  k_bscan<<<1, 128, 0, stream>>>(bsum, eb);
  k_scan2<<<NB, 1024, 0, stream>>>(counts, eb, indptr);
  k_fill<<<(NE + 255) / 256, 256, 0, stream>>>(row, col, indptr, cursor, dinv, edges);

  int gemmGrid = (NN / 16 + 3) / 4;   // 6250 waves, 4 per block
  int aggGrid = (NN + 7) / 8;         // 8 nodes per block (2 per wave x 4 waves)
  int poolGrid = ((NN + PW - 1) / PW * 64 + 255) / 256;

  k_gemm<1><<<gemmGrid, 256, 0, stream>>>(x, WTh, WTl, Hb, NN);
  k_agg<<<aggGrid, 256, 0, stream>>>((const uint2*)Hb, indptr, edges, dinv, b1,
                                     (uint2*)Abuf, 1);
  k_gemm<0><<<gemmGrid, 256, 0, stream>>>(Abuf, WTh + FD * FD, WTl + FD * FD, Hb, NN);
  k_agg<<<aggGrid, 256, 0, stream>>>((const uint2*)Hb, indptr, edges, dinv, b2,
                                     (uint2*)Abuf, 1);
  k_gemm<0><<<gemmGrid, 256, 0, stream>>>(Abuf, WTh + 2 * FD * FD, WTl + 2 * FD * FD, Hb, NN);
  k_agg<<<aggGrid, 256, 0, stream>>>((const uint2*)Hb, indptr, edges, dinv, b3,
                                     (uint2*)Abuf, 0);

  k_pool<<<poolGrid, 256, 0, stream>>>((const unsigned*)Abuf, bat, psum);
  k_head<<<1, 128, 0, stream>>>(psum, starts, ends, Wl, bl, out);
}

// Round 9
// 278.946 us; speedup vs baseline: 1.3867x; 1.3867x over previous
//
#include <hip/hip_runtime.h>

#define NN 100000
#define NE 600000
#define NG 64
#define FD 128
#define NB 98   // scan blocks of 1024: 98*1024 >= NN
#define EPAD 900000  // padded edge capacity: NE + 3*NN
#define NTILE 3125   // 100000 / 32 row-tiles
#define GEMM_BLOCKS 512

typedef __attribute__((ext_vector_type(8))) short s8v;
typedef __attribute__((ext_vector_type(4))) float f4v;

__device__ inline float bflo(unsigned u) { return __uint_as_float(u << 16); }
__device__ inline float bfhi(unsigned u) { return __uint_as_float(u & 0xFFFF0000u); }
__device__ inline unsigned f2bfbits(float f) {  // round-to-nearest-even
  unsigned x = __float_as_uint(f);
  return (x + 0x7FFFu + ((x >> 16) & 1u)) >> 16;
}
__device__ inline unsigned pack2(float a, float b) { return f2bfbits(a) | (f2bfbits(b) << 16); }

// ---------------- weight cast: W f32 [K][N] -> WThi/WTlo bf16 [N][K], 3 weights in one ----------------
__global__ void k_castW3(const float* __restrict__ W1, const float* __restrict__ W2,
                         const float* __restrict__ W3, unsigned short* __restrict__ WTh,
                         unsigned short* __restrict__ WTl) {
  int e = blockIdx.x * 256 + threadIdx.x;   // grid covers 3*FD*FD
  int which = e / (FD * FD);
  int r = e - which * (FD * FD);
  if (which >= 3) return;
  const float* W = which == 0 ? W1 : (which == 1 ? W2 : W3);
  int k = r >> 7, n = r & 127;
  float v = W[r];
  unsigned hb = f2bfbits(v);
  float hf = __uint_as_float(hb << 16);
  unsigned lb = f2bfbits(v - hf);
  WTh[which * FD * FD + n * FD + k] = (unsigned short)hb;
  WTl[which * FD * FD + n * FD + k] = (unsigned short)lb;
}

// ---------------- degree / CSR build ----------------

__global__ void k_init(float* psum) {
  int i = blockIdx.x * 256 + threadIdx.x;
  if (i < NG * FD) psum[i] = 0.f;
}

__global__ void k_count(const int* __restrict__ col, int* __restrict__ counts) {
  int e = blockIdx.x * 256 + threadIdx.x;
  if (e < NE) atomicAdd(&counts[col[e]], 1);
}

__global__ void k_dinv(const int* __restrict__ counts, float* __restrict__ dinv) {
  int n = blockIdx.x * 256 + threadIdx.x;
  if (n < NN) dinv[n] = rsqrtf((float)counts[n] + 1.0f);
}

// 3-phase scan over PADDED counts: ceil(deg/4)*4 per node
__global__ void k_bsum(const int* __restrict__ counts, int* __restrict__ bsum) {
  __shared__ int wsm[16];
  int b = blockIdx.x, t = threadIdx.x;
  int i = b * 1024 + t;
  int x = (i < NN) ? ((counts[i] + 3) & ~3) : 0;
#pragma unroll
  for (int d = 32; d; d >>= 1) x += __shfl_down(x, d);
  if ((t & 63) == 0) wsm[t >> 6] = x;
  __syncthreads();
  if (t < 16) {
    int s = wsm[t];
#pragma unroll
    for (int d = 8; d; d >>= 1) s += __shfl_down(s, d);
    if (t == 0) bsum[b] = s;
  }
}

__global__ void k_bscan(const int* __restrict__ bsum, int* __restrict__ eb) {
  __shared__ int w0;
  int t = threadIdx.x;  // 128
  int x = (t < NB) ? bsum[t] : 0;
  int lane = t & 63;
  int inc = x;
#pragma unroll
  for (int d = 1; d < 64; d <<= 1) { int y = __shfl_up(inc, d); if (lane >= d) inc += y; }
  if (t == 63) w0 = inc;
  __syncthreads();
  int off = (t >= 64) ? w0 : 0;
  if (t < NB) eb[t] = off + inc - x;  // exclusive
}

__global__ void k_scan2(const int* __restrict__ counts, const int* __restrict__ eb,
                        int* __restrict__ indptr) {
  __shared__ int wsm[16];
  int b = blockIdx.x, t = threadIdx.x;
  int i = b * 1024 + t;
  int x = (i < NN) ? ((counts[i] + 3) & ~3) : 0;
  int lane = t & 63, wid = t >> 6;
  int inc = x;
#pragma unroll
  for (int d = 1; d < 64; d <<= 1) { int y = __shfl_up(inc, d); if (lane >= d) inc += y; }
  if (lane == 63) wsm[wid] = inc;
  __syncthreads();
  if (wid == 0) {
    int s = (lane < 16) ? wsm[lane] : 0;
#pragma unroll
    for (int d = 1; d < 16; d <<= 1) { int y = __shfl_up(s, d); if (lane >= d) s += y; }
    if (lane < 16) wsm[lane] = s;
  }
  __syncthreads();
  int woff = wid ? wsm[wid - 1] : 0;
  if (i < NN) indptr[i + 1] = eb[b] + woff + inc;
  if (i == 0) indptr[0] = 0;
}

// combined edge record: {src, nrm}; pad slots stay {0, 0.0f} from memset (exact no-ops)
__global__ void k_fill(const int* __restrict__ row, const int* __restrict__ col,
                       const int* __restrict__ indptr, int* __restrict__ cursor,
                       const float* __restrict__ dinv, uint2* __restrict__ edges) {
  int e = blockIdx.x * 256 + threadIdx.x;
  if (e >= NE) return;
  int c = col[e], r = row[e];
  int p = indptr[c] + atomicAdd(&cursor[c], 1);
  edges[p] = make_uint2((unsigned)r, __float_as_uint(dinv[r] * dinv[c]));
}

// batch is sorted: ranges by boundary detection
__global__ void k_ranges(const int* __restrict__ batch, int* __restrict__ starts,
                         int* __restrict__ ends) {
  int n = blockIdx.x * 256 + threadIdx.x;
  if (n >= NN) return;
  int g = batch[n];
  if (n == 0) {
    starts[g] = 0;
    for (int q = 0; q < g; ++q) { starts[q] = 0; ends[q] = 0; }
  } else {
    int gp = batch[n - 1];
    if (gp != g) {
      ends[gp] = n;
      starts[g] = n;
      for (int q = gp + 1; q < g; ++q) { starts[q] = n; ends[q] = n; }
    }
  }
  if (n == NN - 1) {
    ends[g] = NN;
    for (int q = g + 1; q < NG; ++q) { starts[q] = NN; ends[q] = NN; }
  }
}

// ---------------- MFMA GEMM: Hb[M,128] = A[M,128] @ (WThi+WTlo)^T ----------------
// Whi+Wlo staged ONCE into 64 KB LDS (one barrier), XOR-swizzled 16-B chunks
// (chunk j of row r lives at j^(r&7)) -> conflict-free b128 reads. Then a
// barrier-free persistent loop: each wave owns 32-row tiles (100000 = 3125*32).
// Per n: 8 independent ds_reads feed 16 MFMAs (deep MLP, m97-style pipelining).
template <int F32A>
__global__ __launch_bounds__(256) void k_gemm(const void* __restrict__ Aab,
                                              const unsigned short* __restrict__ WThi,
                                              const unsigned short* __restrict__ WTlo,
                                              unsigned short* __restrict__ Hb) {
  __shared__ unsigned short wt[256 * 128];  // rows 0..127 = hi, 128..255 = lo
  int t = threadIdx.x, lane = t & 63, w = t >> 6;
  int r16 = lane & 15, kg = lane >> 4;

  {  // stage: thread t stages one 128-us row (16 chunks of 8 us), swizzled
    const unsigned short* src = (t < 128) ? (WThi + t * FD) : (WTlo + (t - 128) * FD);
#pragma unroll
    for (int j = 0; j < 16; ++j) {
      int ch = j ^ (t & 7);
      *(s8v*)&wt[t * 128 + ch * 8] = *(const s8v*)(src + j * 8);
    }
  }
  __syncthreads();

  for (int tile = blockIdx.x * 4 + w; tile < NTILE; tile += GEMM_BLOCKS * 4) {
    int rowBase = tile * 32;

    f4v acc[2][8];
#pragma unroll
    for (int rt = 0; rt < 2; ++rt)
#pragma unroll
      for (int n = 0; n < 8; ++n) acc[rt][n] = (f4v){0.f, 0.f, 0.f, 0.f};

    // A fragments: lane holds A[row = rowBase + rt*16 + r16][k = c*32 + kg*8 + j]
    s8v afr[2][4];
#pragma unroll
    for (int rt = 0; rt < 2; ++rt) {
      int ar = rowBase + rt * 16 + r16;
      if (F32A) {
        const float* ap = (const float*)Aab + (size_t)ar * FD + kg * 8;
#pragma unroll
        for (int c = 0; c < 4; ++c) {
          float4 p0 = *(const float4*)(ap + c * 32);
          float4 p1 = *(const float4*)(ap + c * 32 + 4);
          s8v f;
          f[0] = (short)f2bfbits(p0.x); f[1] = (short)f2bfbits(p0.y);
          f[2] = (short)f2bfbits(p0.z); f[3] = (short)f2bfbits(p0.w);
          f[4] = (short)f2bfbits(p1.x); f[5] = (short)f2bfbits(p1.y);
          f[6] = (short)f2bfbits(p1.z); f[7] = (short)f2bfbits(p1.w);
          afr[rt][c] = f;
        }
      } else {
        const unsigned short* ap = (const unsigned short*)Aab + (size_t)ar * FD + kg * 8;
#pragma unroll
        for (int c = 0; c < 4; ++c) afr[rt][c] = *(const s8v*)(ap + c * 32);
      }
    }

#pragma unroll
    for (int n = 0; n < 8; ++n) {
      s8v bh[4], bl[4];
#pragma unroll
      for (int c = 0; c < 4; ++c) {
        int ch = (c * 4 + kg) ^ (r16 & 7);
        bh[c] = *(const s8v*)&wt[(n * 16 + r16) * 128 + ch * 8];
        bl[c] = *(const s8v*)&wt[(128 + n * 16 + r16) * 128 + ch * 8];
      }
#pragma unroll
      for (int c = 0; c < 4; ++c) {
        acc[0][n] = __builtin_amdgcn_mfma_f32_16x16x32_bf16(afr[0][c], bh[c], acc[0][n], 0, 0, 0);
        acc[1][n] = __builtin_amdgcn_mfma_f32_16x16x32_bf16(afr[1][c], bh[c], acc[1][n], 0, 0, 0);
      }
#pragma unroll
      for (int c = 0; c < 4; ++c) {
        acc[0][n] = __builtin_amdgcn_mfma_f32_16x16x32_bf16(afr[0][c], bl[c], acc[0][n], 0, 0, 0);
        acc[1][n] = __builtin_amdgcn_mfma_f32_16x16x32_bf16(afr[1][c], bl[c], acc[1][n], 0, 0, 0);
      }
    }

    // epilogue: D lane layout col = r16, row = kg*4 + j
#pragma unroll
    for (int rt = 0; rt < 2; ++rt)
#pragma unroll
      for (int j = 0; j < 4; ++j) {
        int r = rowBase + rt * 16 + kg * 4 + j;
#pragma unroll
        for (int n = 0; n < 8; ++n)
          Hb[(size_t)r * FD + n * 16 + r16] = (unsigned short)f2bfbits(acc[rt][n][j]);
      }
  }
}

// ---------------- aggregation: 2 nodes per wave (32-lane halves), uint2 lanes ----------------
// CSR segments are padded to multiples of 4 -> single branch-free 4-unrolled loop.
__global__ __launch_bounds__(256) void k_agg(const uint2* __restrict__ H2,
                                             const int* __restrict__ indptr,
                                             const uint2* __restrict__ edges,
                                             const float* __restrict__ dinv,
                                             const float* __restrict__ bias,
                                             uint2* __restrict__ out2, int relu) {
  int wid = (blockIdx.x * 256 + threadIdx.x) >> 6;  // global wave id
  int hl = threadIdx.x & 31;                        // lane within half
  int n = wid * 2 + ((threadIdx.x >> 5) & 1);       // node of this half
  if (n >= NN) return;
  float dv = dinv[n];
  float s2 = dv * dv;
  uint2 u = H2[(size_t)n * 32 + hl];
  float a0 = s2 * bflo(u.x), a1 = s2 * bfhi(u.x);
  float a2 = s2 * bflo(u.y), a3 = s2 * bfhi(u.y);
  int e0 = indptr[n], e1 = indptr[n + 1];  // e1-e0 is a multiple of 4
  for (int e = e0; e < e1; e += 4) {
    uint2 q0 = edges[e], q1 = edges[e + 1], q2 = edges[e + 2], q3 = edges[e + 3];
    uint2 v0 = H2[(size_t)q0.x * 32 + hl];
    uint2 v1 = H2[(size_t)q1.x * 32 + hl];
    uint2 v2 = H2[(size_t)q2.x * 32 + hl];
    uint2 v3 = H2[(size_t)q3.x * 32 + hl];
    float w0 = __uint_as_float(q0.y), w1 = __uint_as_float(q1.y);
    float w2 = __uint_as_float(q2.y), w3 = __uint_as_float(q3.y);
    a0 += w0 * bflo(v0.x); a1 += w0 * bfhi(v0.x); a2 += w0 * bflo(v0.y); a3 += w0 * bfhi(v0.y);
    a0 += w1 * bflo(v1.x); a1 += w1 * bfhi(v1.x); a2 += w1 * bflo(v1.y); a3 += w1 * bfhi(v1.y);
    a0 += w2 * bflo(v2.x); a1 += w2 * bfhi(v2.x); a2 += w2 * bflo(v2.y); a3 += w2 * bfhi(v2.y);
    a0 += w3 * bflo(v3.x); a1 += w3 * bfhi(v3.x); a2 += w3 * bflo(v3.y); a3 += w3 * bfhi(v3.y);
  }
  a0 += bias[hl * 4];
  a1 += bias[hl * 4 + 1];
  a2 += bias[hl * 4 + 2];
  a3 += bias[hl * 4 + 3];
  if (relu) {
    a0 = fmaxf(a0, 0.f); a1 = fmaxf(a1, 0.f);
    a2 = fmaxf(a2, 0.f); a3 = fmaxf(a3, 0.f);
  }
  out2[(size_t)n * 32 + hl] = make_uint2(pack2(a0, a1), pack2(a2, a3));
}

// ---------------- mean pool: wave per 64-node chunk, lanes cover row as bf16x2 ----------------
#define PW 64  // nodes per wave
__global__ __launch_bounds__(256) void k_pool(const unsigned* __restrict__ H2,
                                              const int* __restrict__ batch,
                                              float* __restrict__ psum) {
  int wgl = (blockIdx.x * 256 + threadIdx.x) >> 6;  // global wave id
  int lane = threadIdx.x & 63;
  int n0 = wgl * PW;
  if (n0 >= NN) return;
  int n1 = n0 + PW; if (n1 > NN) n1 = NN;
  int g0 = batch[n0], g1 = batch[n1 - 1];
  float a0 = 0.f, a1 = 0.f;
  if (g0 == g1) {
    int n = n0;
    for (; n + 3 < n1; n += 4) {
      unsigned v0 = H2[(size_t)(n + 0) * 64 + lane];
      unsigned v1 = H2[(size_t)(n + 1) * 64 + lane];
      unsigned v2 = H2[(size_t)(n + 2) * 64 + lane];
      unsigned v3 = H2[(size_t)(n + 3) * 64 + lane];
      a0 += bflo(v0) + bflo(v1) + bflo(v2) + bflo(v3);
      a1 += bfhi(v0) + bfhi(v1) + bfhi(v2) + bfhi(v3);
    }
    for (; n < n1; ++n) {
      unsigned v = H2[(size_t)n * 64 + lane];
      a0 += bflo(v); a1 += bfhi(v);
    }
    atomicAdd(&psum[g0 * FD + lane * 2], a0);
    atomicAdd(&psum[g0 * FD + lane * 2 + 1], a1);
  } else {
    int g = g0;
    for (int n = n0; n < n1; ++n) {
      int gn = batch[n];
      if (gn != g) {
        atomicAdd(&psum[g * FD + lane * 2], a0);
        atomicAdd(&psum[g * FD + lane * 2 + 1], a1);
        a0 = 0.f; a1 = 0.f; g = gn;
      }
      unsigned v = H2[(size_t)n * 64 + lane];
      a0 += bflo(v); a1 += bfhi(v);
    }
    atomicAdd(&psum[g * FD + lane * 2], a0);
    atomicAdd(&psum[g * FD + lane * 2 + 1], a1);
  }
}

__global__ void k_head(const float* __restrict__ psum, const int* __restrict__ starts,
                       const int* __restrict__ ends, const float* __restrict__ Wl,
                       const float* __restrict__ bl, float* __restrict__ out) {
  int t = threadIdx.x;  // 128 = 64 graphs x 2 classes
  int g = t >> 1, c = t & 1;
  int cnt = ends[g] - starts[g];
  if (cnt < 0) cnt = 0;
  float inv = 1.f / (float)(cnt > 0 ? cnt : 1);
  float acc = 0.f;
  for (int k = 0; k < FD; ++k) acc += psum[g * FD + k] * Wl[k * 2 + c];
  out[g * 2 + c] = acc * inv + bl[c];
}

// ---------------- host ----------------

extern "C" void kernel_launch(void* const* d_in, const int* in_sizes, int n_in,
                              void* d_out, int out_size, void* d_ws, size_t ws_size,
                              hipStream_t stream) {
  const float* x  = (const float*)d_in[0];
  const int* ei   = (const int*)d_in[1];
  const int* bat  = (const int*)d_in[2];
  const float* W1 = (const float*)d_in[3];
  const float* b1 = (const float*)d_in[4];
  const float* W2 = (const float*)d_in[5];
  const float* b2 = (const float*)d_in[6];
  const float* W3 = (const float*)d_in[7];
  const float* b3 = (const float*)d_in[8];
  const float* Wl = (const float*)d_in[9];
  const float* bl = (const float*)d_in[10];
  float* out = (float*)d_out;

  char* ws = (char*)d_ws;
  size_t off = 0;
  auto alloc = [&](size_t bytes) {
    void* p = ws + off;
    off += (bytes + 255) & ~(size_t)255;
    return p;
  };
  int* counts  = (int*)alloc(NN * 4);
  int* cursor  = (int*)alloc(NN * 4);
  int* indptr  = (int*)alloc((NN + 1) * 4);
  float* dinv  = (float*)alloc(NN * 4);
  int* bsum    = (int*)alloc(NB * 4);
  int* eb      = (int*)alloc(NB * 4);
  int* starts  = (int*)alloc(NG * 4);
  int* ends    = (int*)alloc(NG * 4);
  float* psum  = (float*)alloc(NG * FD * 4);
  uint2* edges = (uint2*)alloc((size_t)EPAD * 8);
  unsigned short* Hb   = (unsigned short*)alloc((size_t)NN * FD * 2);
  unsigned short* Abuf = (unsigned short*)alloc((size_t)NN * FD * 2);
  unsigned short* WTh  = (unsigned short*)alloc(3 * FD * FD * 2);
  unsigned short* WTl  = (unsigned short*)alloc(3 * FD * FD * 2);

  const int* row = ei;
  const int* col = ei + NE;

  // counts + cursor are adjacent in ws: single memset covers both (and the pad gap)
  hipMemsetAsync(counts, 0, (size_t)((char*)cursor - (char*)counts) + NN * 4, stream);
  hipMemsetAsync(edges, 0, (size_t)EPAD * 8, stream);
  k_init<<<32, 256, 0, stream>>>(psum);
  k_castW3<<<(3 * FD * FD + 255) / 256, 256, 0, stream>>>(W1, W2, W3, WTh, WTl);
  k_ranges<<<(NN + 255) / 256, 256, 0, stream>>>(bat, starts, ends);
  k_count<<<(NE + 255) / 256, 256, 0, stream>>>(col, counts);
  k_dinv<<<(NN + 255) / 256, 256, 0, stream>>>(counts, dinv);
  k_bsum<<<NB, 1024, 0, stream>>>(counts, bsum);
  k_bscan<<<1, 128, 0, stream>>>(bsum, eb);
  k_scan2<<<NB, 1024, 0, stream>>>(counts, eb, indptr);
  k_fill<<<(NE + 255) / 256, 256, 0, stream>>>(row, col, indptr, cursor, dinv, edges);

  int aggGrid = (NN + 7) / 8;         // 8 nodes per block (2 per wave x 4 waves)
  int poolGrid = ((NN + PW - 1) / PW * 64 + 255) / 256;

  k_gemm<1><<<GEMM_BLOCKS, 256, 0, stream>>>(x, WTh, WTl, Hb);
  k_agg<<<aggGrid, 256, 0, stream>>>((const uint2*)Hb, indptr, edges, dinv, b1,
                                     (uint2*)Abuf, 1);
  k_gemm<0><<<GEMM_BLOCKS, 256, 0, stream>>>(Abuf, WTh + FD * FD, WTl + FD * FD, Hb);
  k_agg<<<aggGrid, 256, 0, stream>>>((const uint2*)Hb, indptr, edges, dinv, b2,
                                     (uint2*)Abuf, 1);
  k_gemm<0><<<GEMM_BLOCKS, 256, 0, stream>>>(Abuf, WTh + 2 * FD * FD, WTl + 2 * FD * FD, Hb);
  k_agg<<<aggGrid, 256, 0, stream>>>((const uint2*)Hb, indptr, edges, dinv, b3,
                                     (uint2*)Abuf, 0);

  k_pool<<<poolGrid, 256, 0, stream>>>((const unsigned*)Abuf, bat, psum);
  k_head<<<1, 128, 0, stream>>>(psum, starts, ends, Wl, bl, out);
}